// Round 6
// baseline (147.615 us; speedup 1.0000x reference)
//
#include <hip/hip_runtime.h>
#include <hip/hip_bf16.h>
#include <stdint.h>

#define NN 2048
#define DD 1024
#define HH 16
#define HDD 64
#define QBLK 64
#define KVBLK 64

typedef unsigned short u16;
typedef __attribute__((ext_vector_type(8))) __bf16 bf16x8_t;
typedef __attribute__((ext_vector_type(4))) float f32x4_t;

static __device__ __forceinline__ u16 f2bf(float f) {
  union { float f; uint32_t u; } v; v.f = f;
  uint32_t r = v.u + 0x7FFFu + ((v.u >> 16) & 1u);
  return (u16)(r >> 16);
}

static __device__ __forceinline__ uint32_t packbf2(float a, float b) {
  __hip_bfloat162 h2 = __float22bfloat162_rn(make_float2(a, b));
  union { __hip_bfloat162 hh; uint32_t u; } cvt; cvt.hh = h2;
  return cvt.u;
}

// async global->LDS, 16B per lane. LDS dest must be wave-uniform base + lane*16.
static __device__ __forceinline__ void async_copy16(const void* g, void* l) {
  __builtin_amdgcn_global_load_lds((const __attribute__((address_space(1))) void*)g,
                                   (__attribute__((address_space(3))) void*)l, 16, 0, 0);
}

// ---------------- weight transpose+cast: Wt[n][k] = W[k][n], 4 weights in one launch ----------------
__global__ void transpose_w_kernel(const float* __restrict__ W0, const float* __restrict__ W1,
                                   const float* __restrict__ W2, const float* __restrict__ W3,
                                   u16* __restrict__ Wt) {
  __shared__ float tile[64][65];
  const float* W = blockIdx.y == 0 ? W0 : blockIdx.y == 1 ? W1 : blockIdx.y == 2 ? W2 : W3;
  u16* out = Wt + (size_t)blockIdx.y * DD * DD;
  int bx = blockIdx.x & 15;   // n tile
  int by = blockIdx.x >> 4;   // k tile
  int t = threadIdx.x;
  int c = t & 63, r4 = t >> 6;
#pragma unroll
  for (int i = 0; i < 16; i++) {
    int row = i * 4 + r4;
    tile[row][c] = W[(by * 64 + row) * DD + bx * 64 + c];
  }
  __syncthreads();
#pragma unroll
  for (int i = 0; i < 16; i++) {
    int row = i * 4 + r4;
    out[(bx * 64 + row) * DD + by * 64 + c] = f2bf(tile[c][row]);
  }
}

// ---------------- log-sigmoid gate + fused x->bf16 cast ----------------
__global__ void logf_kernel(const float* __restrict__ x, const float* __restrict__ Wf,
                            float* __restrict__ lf, u16* __restrict__ xb) {
  __shared__ float xs[DD];
  __shared__ float part[16][17];
  int row = blockIdx.x;   // b*N + n
  int t = threadIdx.x;    // 256
  float4 v = *(const float4*)&x[(size_t)row * DD + t * 4];
  *(float4*)&xs[t * 4] = v;
  ushort4 o;
  o.x = f2bf(v.x); o.y = f2bf(v.y); o.z = f2bf(v.z); o.w = f2bf(v.w);
  *(ushort4*)&xb[(size_t)row * DD + t * 4] = o;
  __syncthreads();
  int h = t & 15, chunk = t >> 4;
  float s = 0.f;
#pragma unroll 8
  for (int e = 0; e < 64; e++)
    s += xs[chunk * 64 + e] * Wf[(chunk * 64 + e) * HH + h];
  part[chunk][h] = s;
  __syncthreads();
  if (t < 16) {
    float z = 0.f;
#pragma unroll
    for (int i = 0; i < 16; i++) z += part[i][t];
    float ls = fminf(z, 0.f) - log1pf(__expf(-fabsf(z)));
    int b = row >> 11, n = row & (NN - 1);
    lf[(b * HH + t) * NN + n] = ls;
  }
}

// ---------------- cumsum over n per (b,h): float4/lane, 8 outer iters ----------------
__global__ void cumsum_kernel(const float* __restrict__ lf, float* __restrict__ c) {
  int bh = blockIdx.x;
  int lane = threadIdx.x;  // 64
  const float* in = lf + bh * NN;
  float* out = c + bh * NN;
  float carry = 0.f;
  for (int t0 = 0; t0 < NN; t0 += 256) {
    float4 v = *(const float4*)&in[t0 + lane * 4];
    float s1 = v.x + v.y, s2 = s1 + v.z, s3 = s2 + v.w;
    float incl = s3;
#pragma unroll
    for (int off = 1; off < 64; off <<= 1) {
      float u = __shfl_up(incl, off, 64);
      if (lane >= off) incl += u;
    }
    float excl = incl - s3 + carry;
    float4 o;
    o.x = excl + v.x; o.y = excl + s1; o.z = excl + s2; o.w = excl + s3;
    *(float4*)&out[t0 + lane * 4] = o;
    carry = __shfl(incl, 63, 64) + carry;
  }
}

// ---------------- GEMM 128x128 tile, BK=64, swizzled LDS, XCD-aware block swizzle ----------------
// mode 0 (QKV fused): Wt is [3072][1024]; n-range selects oQ/oK/oV, bf16 [bh][n][hd]
// mode 1 (output):    Wt is [1024][1024]; fp32 flat to oF
__global__ __launch_bounds__(256) void gemm_kernel(const u16* __restrict__ A,
                                                   const u16* __restrict__ Wt,
                                                   u16* __restrict__ oQ, u16* __restrict__ oK,
                                                   u16* __restrict__ oV, float* __restrict__ oF,
                                                   int mode) {
  __shared__ u16 Als[128 * 64];
  __shared__ u16 Bls[128 * 64];
  // XCD-aware swizzle: nwg % 8 == 0 for both launches (768, 256). Each XCD gets a
  // contiguous chunk; within a chunk n varies fastest -> A-panel reused in that XCD's L2.
  int nwg = gridDim.x * gridDim.y;
  int flat = blockIdx.y * gridDim.x + blockIdx.x;
  int cpx = nwg >> 3;
  int f2 = (flat & 7) * cpx + (flat >> 3);
  int m0 = (f2 / gridDim.x) * 128, n0 = (f2 % gridDim.x) * 128;
  int tid = threadIdx.x;
  int lane = tid & 63, w = tid >> 6;
  int wm = w >> 1, wn = w & 1;
  int lr = lane & 15, lg = lane >> 4;

  // staging: slots s = tid + j*256 (j=0..3). row = s>>3, chunk = s&7 (16B units).
  // LDS linear at s*16; swizzle folded into SOURCE chunk: chunk ^ (row&7).
  const u16* gA[4]; const u16* gB[4]; u16* lA[4]; u16* lB[4];
#pragma unroll
  for (int j = 0; j < 4; j++) {
    int s = tid + j * 256;
    int row = s >> 3, ch = s & 7;
    int scol = (ch ^ (row & 7)) * 8;
    gA[j] = &A [(size_t)(m0 + row) * DD + scol];
    gB[j] = &Wt[(size_t)(n0 + row) * DD + scol];
    lA[j] = &Als[s * 8];
    lB[j] = &Bls[s * 8];
  }

  f32x4_t acc[4][4];
#pragma unroll
  for (int i = 0; i < 4; i++)
#pragma unroll
    for (int j = 0; j < 4; j++) acc[i][j] = (f32x4_t){0.f, 0.f, 0.f, 0.f};

  for (int kt = 0; kt < DD; kt += 64) {
    __syncthreads();
#pragma unroll
    for (int j = 0; j < 4; j++) {
      async_copy16(gA[j] + kt, lA[j]);
      async_copy16(gB[j] + kt, lB[j]);
    }
    __syncthreads();
#pragma unroll
    for (int kk = 0; kk < 2; kk++) {
      bf16x8_t af[4], bfv[4];
#pragma unroll
      for (int mi = 0; mi < 4; mi++) {
        int row = wm * 64 + mi * 16 + lr;
        int boff = (row * 128 + kk * 64 + lg * 16) ^ ((row & 7) << 4);
        af[mi] = *(const bf16x8_t*)((const char*)Als + boff);
      }
#pragma unroll
      for (int ni = 0; ni < 4; ni++) {
        int row = wn * 64 + ni * 16 + lr;
        int boff = (row * 128 + kk * 64 + lg * 16) ^ ((row & 7) << 4);
        bfv[ni] = *(const bf16x8_t*)((const char*)Bls + boff);
      }
      __builtin_amdgcn_s_setprio(1);
#pragma unroll
      for (int mi = 0; mi < 4; mi++)
#pragma unroll
        for (int ni = 0; ni < 4; ni++)
          acc[mi][ni] = __builtin_amdgcn_mfma_f32_16x16x32_bf16(af[mi], bfv[ni], acc[mi][ni], 0, 0, 0);
      __builtin_amdgcn_s_setprio(0);
    }
  }

  if (mode == 1) {
#pragma unroll
    for (int mi = 0; mi < 4; mi++)
#pragma unroll
      for (int ni = 0; ni < 4; ni++) {
        int gcol = n0 + wn * 64 + ni * 16 + lr;
#pragma unroll
        for (int r = 0; r < 4; r++) {
          int grow = m0 + wm * 64 + mi * 16 + lg * 4 + r;
          oF[(size_t)grow * DD + gcol] = acc[mi][ni][r];
        }
      }
  } else {
    int which = n0 >> 10;
    u16* outp = which == 0 ? oQ : which == 1 ? oK : oV;
    int nl0 = n0 & 1023;
#pragma unroll
    for (int mi = 0; mi < 4; mi++)
#pragma unroll
      for (int ni = 0; ni < 4; ni++) {
        int gcol = nl0 + wn * 64 + ni * 16 + lr;
        int h = gcol >> 6, hd = gcol & 63;
#pragma unroll
        for (int r = 0; r < 4; r++) {
          int grow = m0 + wm * 64 + mi * 16 + lg * 4 + r;
          int b = grow >> 11, n = grow & (NN - 1);
          outp[((size_t)(b * HH + h) * NN + n) * HDD + hd] = f2bf(acc[mi][ni][r]);
        }
      }
  }
}

// ---------------- V transpose: [bh][n][hd] -> [bh][hd][n] ----------------
__global__ void transpose_v_kernel(const u16* __restrict__ Vtmp, u16* __restrict__ Vt) {
  __shared__ u16 tile[64][80];
  int bh = blockIdx.y;
  int n0 = blockIdx.x * 64;
  int t = threadIdx.x;
  const u16* src = Vtmp + (size_t)bh * NN * HDD;
  u16* dst = Vt + (size_t)bh * HDD * NN;
#pragma unroll
  for (int it = 0; it < 2; it++) {
    int cc = t + it * 256;
    int row = cc >> 3, p = cc & 7;
    *(uint4*)&tile[row][p * 8] = *(const uint4*)&src[(size_t)(n0 + row) * HDD + p * 8];
  }
  __syncthreads();
#pragma unroll
  for (int it = 0; it < 2; it++) {
    int cc = t + it * 256;
    int row = cc >> 3, p = cc & 7;
    union { u16 v[8]; uint4 q; } tmp;
#pragma unroll
    for (int e = 0; e < 8; e++) tmp.v[e] = tile[p * 8 + e][row];
    *(uint4*)&dst[(size_t)row * NN + n0 + p * 8] = tmp.q;
  }
}

// ---------------- flash attention with decay bias, SWAPPED QK^T ----------------
// mfma(K,Q) -> S^T: lane owns ONE q-row (i = lane&15), 16 j-values per KV tile.
// cq/lsum scalar per lane; P write = 4x ds_write_b64; PV = mfma(V^T, P) -> D[d][i];
// output = packed 8B stores. Fixed-max softmax, deferred l, paired tiles, dbuf staging.
__global__ __launch_bounds__(256) void attn_kernel(const u16* __restrict__ Q,
                                                   const u16* __restrict__ K,
                                                   const u16* __restrict__ Vt,
                                                   const float* __restrict__ cw,
                                                   u16* __restrict__ O) {
  __shared__ u16 Kls[2][KVBLK * 64];
  __shared__ u16 Vls[2][64 * KVBLK];
  __shared__ u16 Pls[4][16 * 64];
  int pidx = blockIdx.x, bh = blockIdx.y;
  int tid = threadIdx.x;
  int lane = tid & 63, w = tid >> 6;
  int lr = lane & 15, lg = lane >> 4;
  const u16* Qh = Q + (size_t)bh * NN * HDD;
  const u16* Kh = K + (size_t)bh * NN * HDD;
  const u16* Vh = Vt + (size_t)bh * HDD * NN;
  const float* ch = cw + bh * NN;
  int b = bh >> 4, h = bh & 15;

  // staging: 512 slots of 16B per 8KB tile; LDS linear at slot*16B;
  // swizzle folded into SOURCE chunk: chunk ^ (row&7).
  int s0 = tid, s1 = tid + 256;
  int r0 = s0 >> 3, p0 = s0 & 7;
  int r1 = s1 >> 3, p1 = s1 & 7;
  const u16* gk0 = &Kh[(size_t)r0 * HDD + ((p0 ^ (r0 & 7)) * 8)];
  const u16* gk1 = &Kh[(size_t)r1 * HDD + ((p1 ^ (r1 & 7)) * 8)];
  const u16* gv0 = &Vh[(size_t)r0 * NN + ((p0 ^ (r0 & 7)) * 8)];
  const u16* gv1 = &Vh[(size_t)r1 * NN + ((p1 ^ (r1 & 7)) * 8)];

  for (int which = 0; which < 2; which++) {
    int tile = which == 0 ? (31 - pidx) : pidx;
    int qb = tile * QBLK + w * 16;
    int iq = qb + lr;  // this lane's q-row

    bf16x8_t qf[2];
#pragma unroll
    for (int s = 0; s < 2; s++)
      qf[s] = *(const bf16x8_t*)&Qh[(size_t)iq * HDD + s * 32 + lg * 8];
    float cq = ch[iq];

    float lsum = 0.f;
    f32x4_t oacc[4];
#pragma unroll
    for (int fn = 0; fn < 4; fn++) oacc[fn] = (f32x4_t){0.f, 0.f, 0.f, 0.f};

    // prologue: stage kv tile 0 into buffer 0
    async_copy16(gk0, &Kls[0][s0 * 8]);
    async_copy16(gk1, &Kls[0][s1 * 8]);
    async_copy16(gv0, &Vls[0][s0 * 8]);
    async_copy16(gv1, &Vls[0][s1 * 8]);
    __syncthreads();

    int cur = 0;
    for (int kvt = 0; kvt <= tile; kvt++) {
      // stage next tile into the other buffer BEFORE computing this one
      if (kvt < tile) {
        int nb = cur ^ 1;
        size_t kvn = (size_t)(kvt + 1) * KVBLK;
        async_copy16(gk0 + kvn * HDD, &Kls[nb][s0 * 8]);
        async_copy16(gk1 + kvn * HDD, &Kls[nb][s1 * 8]);
        async_copy16(gv0 + kvn, &Vls[nb][s0 * 8]);
        async_copy16(gv1 + kvn, &Vls[nb][s1 * 8]);
      }
      int kv0 = kvt * KVBLK;
      const u16* Kb = Kls[cur];
      const u16* Vb = Vls[cur];
      float4 ckv[4];
#pragma unroll
      for (int f = 0; f < 4; f++)
        ckv[f] = *(const float4*)&ch[kv0 + f * 16 + lg * 4];

      // S^T = K . Q^T : lane holds col i=lr, rows j = kv0 + f*16 + lg*4 + r
      f32x4_t sacc[4];
#pragma unroll
      for (int f = 0; f < 4; f++) sacc[f] = (f32x4_t){0.f, 0.f, 0.f, 0.f};
      __builtin_amdgcn_s_setprio(1);
#pragma unroll
      for (int f = 0; f < 4; f++) {
        int row = f * 16 + lr;
#pragma unroll
        for (int s = 0; s < 2; s++) {
          int boff = (row * 128 + s * 64 + lg * 16) ^ ((row & 7) << 4);
          bf16x8_t kf = *(const bf16x8_t*)((const char*)Kb + boff);
          sacc[f] = __builtin_amdgcn_mfma_f32_16x16x32_bf16(kf, qf[s], sacc[f], 0, 0, 0);
        }
      }
      __builtin_amdgcn_s_setprio(0);

      // fixed-max softmax: e = exp(s*scale + cq - ck); scalar lsum
      bool diag = (kvt == tile);
      float pv[4][4];
#pragma unroll
      for (int f = 0; f < 4; f++) {
        const float* ckp = &ckv[f].x;
#pragma unroll
        for (int r = 0; r < 4; r++) {
          float val = fmaf(sacc[f][r], 0.125f, cq - ckp[r]);
          float e = __expf(val);
          if (diag && (kv0 + f * 16 + lg * 4 + r) > iq) e = 0.f;
          pv[f][r] = e; lsum += e;
        }
      }

      // P -> LDS: row = lr (q-row), cols j-local = f*16+lg*4+r; 4x b64 writes
      u16* pw = (u16*)Pls[w];
#pragma unroll
      for (int f = 0; f < 4; f++) {
        uint2 d2;
        d2.x = packbf2(pv[f][0], pv[f][1]);
        d2.y = packbf2(pv[f][2], pv[f][3]);
        int boff = (lr * 128 + (f * 16 + lg * 4) * 2) ^ ((lr & 7) << 4);
        *(uint2*)((char*)pw + boff) = d2;
      }
      // read P as B-fragment: slot (lg,e) = P[i=lr][j = s*32+8lg+e]
      bf16x8_t pa[2];
#pragma unroll
      for (int s = 0; s < 2; s++) {
        int boff = (lr * 128 + s * 64 + lg * 16) ^ ((lr & 7) << 4);
        pa[s] = *(const bf16x8_t*)((const char*)pw + boff);
      }
      // O^T += V^T . P : A = V^T rows (m=d), B = P (n=i)
      __builtin_amdgcn_s_setprio(1);
#pragma unroll
      for (int fn = 0; fn < 4; fn++) {
        int row = fn * 16 + lr;
#pragma unroll
        for (int s = 0; s < 2; s++) {
          int boff = (row * 128 + s * 64 + lg * 16) ^ ((row & 7) << 4);
          bf16x8_t vf = *(const bf16x8_t*)((const char*)Vb + boff);
          oacc[fn] = __builtin_amdgcn_mfma_f32_16x16x32_bf16(vf, pa[s], oacc[fn], 0, 0, 0);
        }
      }
      __builtin_amdgcn_s_setprio(0);
      __syncthreads();
      cur ^= 1;
    }

    // l-reduce over the 4 lanes sharing lr (j-partials live in lg groups)
    lsum += __shfl_xor(lsum, 16, 64);
    lsum += __shfl_xor(lsum, 32, 64);
    float rinv = 1.0f / lsum;

    // output: lane's q-row iq, hd = fn*16 + lg*4 + r -> packed 8B stores
    u16* orow = O + ((size_t)(b * NN + iq)) * DD + h * HDD;
#pragma unroll
    for (int fn = 0; fn < 4; fn++) {
      ushort4 o4;
      o4.x = f2bf(oacc[fn][0] * rinv);
      o4.y = f2bf(oacc[fn][1] * rinv);
      o4.z = f2bf(oacc[fn][2] * rinv);
      o4.w = f2bf(oacc[fn][3] * rinv);
      *(ushort4*)&orow[fn * 16 + lg * 4] = o4;
    }
  }
}

extern "C" void kernel_launch(void* const* d_in, const int* in_sizes, int n_in,
                              void* d_out, int out_size, void* d_ws, size_t ws_size,
                              hipStream_t stream) {
  const float* x  = (const float*)d_in[0];
  const float* Wq = (const float*)d_in[1];
  const float* Wk = (const float*)d_in[2];
  const float* Wv = (const float*)d_in[3];
  const float* Wo = (const float*)d_in[4];
  const float* Wf = (const float*)d_in[5];
  float* out = (float*)d_out;
  char* ws = (char*)d_ws;
  const size_t MB = 1024 * 1024;
  u16* x_bf  = (u16*)(ws + 0);        // 8 MB
  u16* WqkvT = (u16*)(ws + 8 * MB);   // 6 MB: WqT | WkT | WvT contiguous [3072][1024]
  u16* WoT   = (u16*)(ws + 14 * MB);  // 2 MB
  u16* Qw    = (u16*)(ws + 16 * MB);  // 8 MB [bh][n][hd]
  u16* Kw    = (u16*)(ws + 24 * MB);  // 8 MB
  u16* Vw    = (u16*)(ws + 32 * MB);  // 8 MB [bh][hd][n]
  u16* Ow    = (u16*)(ws + 40 * MB);  // 8 MB [b n d]
  float* lf  = (float*)(ws + 48 * MB);            // 256 KB
  float* cwp = (float*)(ws + 48 * MB + 262144);   // 256 KB
  u16* Vtmp  = (u16*)(ws + 49 * MB);  // 8 MB [bh][n][hd]

  transpose_w_kernel<<<dim3(256, 4), 256, 0, stream>>>(Wq, Wk, Wv, Wo, WqkvT);
  logf_kernel<<<4096, 256, 0, stream>>>(x, Wf, lf, x_bf);
  cumsum_kernel<<<32, 64, 0, stream>>>(lf, cwp);
  // fused QKV GEMM: N = 3072
  gemm_kernel<<<dim3(24, 32), 256, 0, stream>>>(x_bf, WqkvT, Qw, Kw, Vtmp, nullptr, 0);
  transpose_v_kernel<<<dim3(32, 32), 256, 0, stream>>>(Vtmp, Vw);
  attn_kernel<<<dim3(16, 32), 256, 0, stream>>>(Qw, Kw, Vw, cwp, Ow);
  gemm_kernel<<<dim3(8, 32), 256, 0, stream>>>(Ow, WqkvT + (size_t)3 * DD * DD, nullptr, nullptr, nullptr, out, 1);
}

// Round 7
// 134.997 us; speedup vs baseline: 1.0935x; 1.0935x over previous
//
#include <hip/hip_runtime.h>
#include <hip/hip_bf16.h>
#include <stdint.h>

#define NN 2048
#define DD 1024
#define HH 16
#define HDD 64
#define QBLK 64
#define KVBLK 64

typedef unsigned short u16;
typedef __attribute__((ext_vector_type(8))) __bf16 bf16x8_t;
typedef __attribute__((ext_vector_type(4))) float f32x4_t;

static __device__ __forceinline__ u16 f2bf(float f) {
  union { float f; uint32_t u; } v; v.f = f;
  uint32_t r = v.u + 0x7FFFu + ((v.u >> 16) & 1u);
  return (u16)(r >> 16);
}

static __device__ __forceinline__ uint32_t packbf2(float a, float b) {
  __hip_bfloat162 h2 = __float22bfloat162_rn(make_float2(a, b));
  union { __hip_bfloat162 hh; uint32_t u; } cvt; cvt.hh = h2;
  return cvt.u;
}

// async global->LDS, 16B per lane. LDS dest must be wave-uniform base + lane*16.
static __device__ __forceinline__ void async_copy16(const void* g, void* l) {
  __builtin_amdgcn_global_load_lds((const __attribute__((address_space(1))) void*)g,
                                   (__attribute__((address_space(3))) void*)l, 16, 0, 0);
}

// ---------------- weight transpose+cast: Wt[n][k] = W[k][n], 4 weights in one launch ----------------
__global__ void transpose_w_kernel(const float* __restrict__ W0, const float* __restrict__ W1,
                                   const float* __restrict__ W2, const float* __restrict__ W3,
                                   u16* __restrict__ Wt) {
  __shared__ float tile[64][65];
  const float* W = blockIdx.y == 0 ? W0 : blockIdx.y == 1 ? W1 : blockIdx.y == 2 ? W2 : W3;
  u16* out = Wt + (size_t)blockIdx.y * DD * DD;
  int bx = blockIdx.x & 15;   // n tile
  int by = blockIdx.x >> 4;   // k tile
  int t = threadIdx.x;
  int c = t & 63, r4 = t >> 6;
#pragma unroll
  for (int i = 0; i < 16; i++) {
    int row = i * 4 + r4;
    tile[row][c] = W[(by * 64 + row) * DD + bx * 64 + c];
  }
  __syncthreads();
#pragma unroll
  for (int i = 0; i < 16; i++) {
    int row = i * 4 + r4;
    out[(bx * 64 + row) * DD + by * 64 + c] = f2bf(tile[c][row]);
  }
}

// ---------------- log-sigmoid gate + fused x->bf16 cast ----------------
__global__ void logf_kernel(const float* __restrict__ x, const float* __restrict__ Wf,
                            float* __restrict__ lf, u16* __restrict__ xb) {
  __shared__ float xs[DD];
  __shared__ float part[16][17];
  int row = blockIdx.x;   // b*N + n
  int t = threadIdx.x;    // 256
  float4 v = *(const float4*)&x[(size_t)row * DD + t * 4];
  *(float4*)&xs[t * 4] = v;
  ushort4 o;
  o.x = f2bf(v.x); o.y = f2bf(v.y); o.z = f2bf(v.z); o.w = f2bf(v.w);
  *(ushort4*)&xb[(size_t)row * DD + t * 4] = o;
  __syncthreads();
  int h = t & 15, chunk = t >> 4;
  float s = 0.f;
#pragma unroll 8
  for (int e = 0; e < 64; e++)
    s += xs[chunk * 64 + e] * Wf[(chunk * 64 + e) * HH + h];
  part[chunk][h] = s;
  __syncthreads();
  if (t < 16) {
    float z = 0.f;
#pragma unroll
    for (int i = 0; i < 16; i++) z += part[i][t];
    float ls = fminf(z, 0.f) - log1pf(__expf(-fabsf(z)));
    int b = row >> 11, n = row & (NN - 1);
    lf[(b * HH + t) * NN + n] = ls;
  }
}

// ---------------- cumsum over n per (b,h): float4/lane, 8 outer iters ----------------
__global__ void cumsum_kernel(const float* __restrict__ lf, float* __restrict__ c) {
  int bh = blockIdx.x;
  int lane = threadIdx.x;  // 64
  const float* in = lf + bh * NN;
  float* out = c + bh * NN;
  float carry = 0.f;
  for (int t0 = 0; t0 < NN; t0 += 256) {
    float4 v = *(const float4*)&in[t0 + lane * 4];
    float s1 = v.x + v.y, s2 = s1 + v.z, s3 = s2 + v.w;
    float incl = s3;
#pragma unroll
    for (int off = 1; off < 64; off <<= 1) {
      float u = __shfl_up(incl, off, 64);
      if (lane >= off) incl += u;
    }
    float excl = incl - s3 + carry;
    float4 o;
    o.x = excl + v.x; o.y = excl + s1; o.z = excl + s2; o.w = excl + s3;
    *(float4*)&out[t0 + lane * 4] = o;
    carry = __shfl(incl, 63, 64) + carry;
  }
}

// ---------------- GEMM 128x128 tile, BK=64, swizzled LDS (round-5 proven state) ----------------
// mode 0 (QKV fused): Wt is [3072][1024]; n-range selects oQ/oK/oV, bf16 [bh][n][hd]
// mode 1 (output):    Wt is [1024][1024]; fp32 flat to oF
__global__ __launch_bounds__(256) void gemm_kernel(const u16* __restrict__ A,
                                                   const u16* __restrict__ Wt,
                                                   u16* __restrict__ oQ, u16* __restrict__ oK,
                                                   u16* __restrict__ oV, float* __restrict__ oF,
                                                   int mode) {
  __shared__ u16 Als[128 * 64];
  __shared__ u16 Bls[128 * 64];
  int m0 = blockIdx.y * 128, n0 = blockIdx.x * 128;
  int tid = threadIdx.x;
  int lane = tid & 63, w = tid >> 6;
  int wm = w >> 1, wn = w & 1;
  int lr = lane & 15, lg = lane >> 4;

  // staging: slots s = tid + j*256 (j=0..3). row = s>>3, chunk = s&7 (16B units).
  // LDS linear at s*16; swizzle folded into SOURCE chunk: chunk ^ (row&7).
  const u16* gA[4]; const u16* gB[4]; u16* lA[4]; u16* lB[4];
#pragma unroll
  for (int j = 0; j < 4; j++) {
    int s = tid + j * 256;
    int row = s >> 3, ch = s & 7;
    int scol = (ch ^ (row & 7)) * 8;
    gA[j] = &A [(size_t)(m0 + row) * DD + scol];
    gB[j] = &Wt[(size_t)(n0 + row) * DD + scol];
    lA[j] = &Als[s * 8];
    lB[j] = &Bls[s * 8];
  }

  f32x4_t acc[4][4];
#pragma unroll
  for (int i = 0; i < 4; i++)
#pragma unroll
    for (int j = 0; j < 4; j++) acc[i][j] = (f32x4_t){0.f, 0.f, 0.f, 0.f};

  for (int kt = 0; kt < DD; kt += 64) {
    __syncthreads();
#pragma unroll
    for (int j = 0; j < 4; j++) {
      async_copy16(gA[j] + kt, lA[j]);
      async_copy16(gB[j] + kt, lB[j]);
    }
    __syncthreads();
#pragma unroll
    for (int kk = 0; kk < 2; kk++) {
      bf16x8_t af[4], bfv[4];
#pragma unroll
      for (int mi = 0; mi < 4; mi++) {
        int row = wm * 64 + mi * 16 + lr;
        int boff = (row * 128 + kk * 64 + lg * 16) ^ ((row & 7) << 4);
        af[mi] = *(const bf16x8_t*)((const char*)Als + boff);
      }
#pragma unroll
      for (int ni = 0; ni < 4; ni++) {
        int row = wn * 64 + ni * 16 + lr;
        int boff = (row * 128 + kk * 64 + lg * 16) ^ ((row & 7) << 4);
        bfv[ni] = *(const bf16x8_t*)((const char*)Bls + boff);
      }
#pragma unroll
      for (int mi = 0; mi < 4; mi++)
#pragma unroll
        for (int ni = 0; ni < 4; ni++)
          acc[mi][ni] = __builtin_amdgcn_mfma_f32_16x16x32_bf16(af[mi], bfv[ni], acc[mi][ni], 0, 0, 0);
    }
  }

  if (mode == 1) {
#pragma unroll
    for (int mi = 0; mi < 4; mi++)
#pragma unroll
      for (int ni = 0; ni < 4; ni++) {
        int gcol = n0 + wn * 64 + ni * 16 + lr;
#pragma unroll
        for (int r = 0; r < 4; r++) {
          int grow = m0 + wm * 64 + mi * 16 + lg * 4 + r;
          oF[(size_t)grow * DD + gcol] = acc[mi][ni][r];
        }
      }
  } else {
    int which = n0 >> 10;
    u16* outp = which == 0 ? oQ : which == 1 ? oK : oV;
    int nl0 = n0 & 1023;
#pragma unroll
    for (int mi = 0; mi < 4; mi++)
#pragma unroll
      for (int ni = 0; ni < 4; ni++) {
        int gcol = nl0 + wn * 64 + ni * 16 + lr;
        int h = gcol >> 6, hd = gcol & 63;
#pragma unroll
        for (int r = 0; r < 4; r++) {
          int grow = m0 + wm * 64 + mi * 16 + lg * 4 + r;
          int b = grow >> 11, n = grow & (NN - 1);
          outp[((size_t)(b * HH + h) * NN + n) * HDD + hd] = f2bf(acc[mi][ni][r]);
        }
      }
  }
}

// ---------------- V transpose: [bh][n][hd] -> [bh][hd][n] ----------------
__global__ void transpose_v_kernel(const u16* __restrict__ Vtmp, u16* __restrict__ Vt) {
  __shared__ u16 tile[64][80];
  int bh = blockIdx.y;
  int n0 = blockIdx.x * 64;
  int t = threadIdx.x;
  const u16* src = Vtmp + (size_t)bh * NN * HDD;
  u16* dst = Vt + (size_t)bh * HDD * NN;
#pragma unroll
  for (int it = 0; it < 2; it++) {
    int cc = t + it * 256;
    int row = cc >> 3, p = cc & 7;
    *(uint4*)&tile[row][p * 8] = *(const uint4*)&src[(size_t)(n0 + row) * HDD + p * 8];
  }
  __syncthreads();
#pragma unroll
  for (int it = 0; it < 2; it++) {
    int cc = t + it * 256;
    int row = cc >> 3, p = cc & 7;
    union { u16 v[8]; uint4 q; } tmp;
#pragma unroll
    for (int e = 0; e < 8; e++) tmp.v[e] = tile[p * 8 + e][row];
    *(uint4*)&dst[(size_t)row * NN + n0 + p * 8] = tmp.q;
  }
}

// ---------------- flash attention with decay bias, SWAPPED QK^T, XCD-aware grid ----------------
// XCD swizzle: swz = (flat&7)*64 + flat>>3 -> each XCD exclusively serves 4 bh,
// so K/V (2MB per 4 bh) stays in that XCD's 4MB L2 instead of being fetched by all 8.
__global__ __launch_bounds__(256) void attn_kernel(const u16* __restrict__ Q,
                                                   const u16* __restrict__ K,
                                                   const u16* __restrict__ Vt,
                                                   const float* __restrict__ cw,
                                                   u16* __restrict__ O) {
  __shared__ u16 Kls[2][KVBLK * 64];
  __shared__ u16 Vls[2][64 * KVBLK];
  __shared__ u16 Pls[4][16 * 64];
  int flat = blockIdx.y * gridDim.x + blockIdx.x;  // grid (16, 32) = 512
  int swz = (flat & 7) * 64 + (flat >> 3);         // bijective, bh-contiguous per XCD
  int pidx = swz & 15, bh = swz >> 4;
  int tid = threadIdx.x;
  int lane = tid & 63, w = tid >> 6;
  int lr = lane & 15, lg = lane >> 4;
  const u16* Qh = Q + (size_t)bh * NN * HDD;
  const u16* Kh = K + (size_t)bh * NN * HDD;
  const u16* Vh = Vt + (size_t)bh * HDD * NN;
  const float* ch = cw + bh * NN;
  int b = bh >> 4, h = bh & 15;

  // staging: 512 slots of 16B per 8KB tile; LDS linear at slot*16B;
  // swizzle folded into SOURCE chunk: chunk ^ (row&7).
  int s0 = tid, s1 = tid + 256;
  int r0 = s0 >> 3, p0 = s0 & 7;
  int r1 = s1 >> 3, p1 = s1 & 7;
  const u16* gk0 = &Kh[(size_t)r0 * HDD + ((p0 ^ (r0 & 7)) * 8)];
  const u16* gk1 = &Kh[(size_t)r1 * HDD + ((p1 ^ (r1 & 7)) * 8)];
  const u16* gv0 = &Vh[(size_t)r0 * NN + ((p0 ^ (r0 & 7)) * 8)];
  const u16* gv1 = &Vh[(size_t)r1 * NN + ((p1 ^ (r1 & 7)) * 8)];

  for (int which = 0; which < 2; which++) {
    int tile = which == 0 ? (31 - pidx) : pidx;
    int qb = tile * QBLK + w * 16;
    int iq = qb + lr;  // this lane's q-row

    bf16x8_t qf[2];
#pragma unroll
    for (int s = 0; s < 2; s++)
      qf[s] = *(const bf16x8_t*)&Qh[(size_t)iq * HDD + s * 32 + lg * 8];
    float cq = ch[iq];

    float lsum = 0.f;
    f32x4_t oacc[4];
#pragma unroll
    for (int fn = 0; fn < 4; fn++) oacc[fn] = (f32x4_t){0.f, 0.f, 0.f, 0.f};

    // prologue: stage kv tile 0 into buffer 0
    async_copy16(gk0, &Kls[0][s0 * 8]);
    async_copy16(gk1, &Kls[0][s1 * 8]);
    async_copy16(gv0, &Vls[0][s0 * 8]);
    async_copy16(gv1, &Vls[0][s1 * 8]);
    __syncthreads();

    int cur = 0;
    for (int kvt = 0; kvt <= tile; kvt++) {
      // stage next tile into the other buffer BEFORE computing this one
      if (kvt < tile) {
        int nb = cur ^ 1;
        size_t kvn = (size_t)(kvt + 1) * KVBLK;
        async_copy16(gk0 + kvn * HDD, &Kls[nb][s0 * 8]);
        async_copy16(gk1 + kvn * HDD, &Kls[nb][s1 * 8]);
        async_copy16(gv0 + kvn, &Vls[nb][s0 * 8]);
        async_copy16(gv1 + kvn, &Vls[nb][s1 * 8]);
      }
      int kv0 = kvt * KVBLK;
      const u16* Kb = Kls[cur];
      const u16* Vb = Vls[cur];
      float4 ckv[4];
#pragma unroll
      for (int f = 0; f < 4; f++)
        ckv[f] = *(const float4*)&ch[kv0 + f * 16 + lg * 4];

      // S^T = K . Q^T : lane holds col i=lr, rows j = kv0 + f*16 + lg*4 + r
      f32x4_t sacc[4];
#pragma unroll
      for (int f = 0; f < 4; f++) sacc[f] = (f32x4_t){0.f, 0.f, 0.f, 0.f};
      __builtin_amdgcn_s_setprio(1);
#pragma unroll
      for (int f = 0; f < 4; f++) {
        int row = f * 16 + lr;
#pragma unroll
        for (int s = 0; s < 2; s++) {
          int boff = (row * 128 + s * 64 + lg * 16) ^ ((row & 7) << 4);
          bf16x8_t kf = *(const bf16x8_t*)((const char*)Kb + boff);
          sacc[f] = __builtin_amdgcn_mfma_f32_16x16x32_bf16(kf, qf[s], sacc[f], 0, 0, 0);
        }
      }
      __builtin_amdgcn_s_setprio(0);

      // fixed-max softmax: e = exp(s*scale + cq - ck); scalar lsum
      bool diag = (kvt == tile);
      float pv[4][4];
#pragma unroll
      for (int f = 0; f < 4; f++) {
        const float* ckp = &ckv[f].x;
#pragma unroll
        for (int r = 0; r < 4; r++) {
          float val = fmaf(sacc[f][r], 0.125f, cq - ckp[r]);
          float e = __expf(val);
          if (diag && (kv0 + f * 16 + lg * 4 + r) > iq) e = 0.f;
          pv[f][r] = e; lsum += e;
        }
      }

      // P -> LDS: row = lr (q-row), cols j-local = f*16+lg*4+r; 4x b64 writes
      u16* pw = (u16*)Pls[w];
#pragma unroll
      for (int f = 0; f < 4; f++) {
        uint2 d2;
        d2.x = packbf2(pv[f][0], pv[f][1]);
        d2.y = packbf2(pv[f][2], pv[f][3]);
        int boff = (lr * 128 + (f * 16 + lg * 4) * 2) ^ ((lr & 7) << 4);
        *(uint2*)((char*)pw + boff) = d2;
      }
      // read P as B-fragment: slot (lg,e) = P[i=lr][j = s*32+8lg+e]
      bf16x8_t pa[2];
#pragma unroll
      for (int s = 0; s < 2; s++) {
        int boff = (lr * 128 + s * 64 + lg * 16) ^ ((lr & 7) << 4);
        pa[s] = *(const bf16x8_t*)((const char*)pw + boff);
      }
      // O^T += V^T . P : A = V^T rows (m=d), B = P (n=i)
      __builtin_amdgcn_s_setprio(1);
#pragma unroll
      for (int fn = 0; fn < 4; fn++) {
        int row = fn * 16 + lr;
#pragma unroll
        for (int s = 0; s < 2; s++) {
          int boff = (row * 128 + s * 64 + lg * 16) ^ ((row & 7) << 4);
          bf16x8_t vf = *(const bf16x8_t*)((const char*)Vb + boff);
          oacc[fn] = __builtin_amdgcn_mfma_f32_16x16x32_bf16(vf, pa[s], oacc[fn], 0, 0, 0);
        }
      }
      __builtin_amdgcn_s_setprio(0);
      __syncthreads();
      cur ^= 1;
    }

    // l-reduce over the 4 lanes sharing lr
    lsum += __shfl_xor(lsum, 16, 64);
    lsum += __shfl_xor(lsum, 32, 64);
    float rinv = 1.0f / lsum;

    // output: lane's q-row iq, hd = fn*16 + lg*4 + r -> packed 8B stores
    u16* orow = O + ((size_t)(b * NN + iq)) * DD + h * HDD;
#pragma unroll
    for (int fn = 0; fn < 4; fn++) {
      ushort4 o4;
      o4.x = f2bf(oacc[fn][0] * rinv);
      o4.y = f2bf(oacc[fn][1] * rinv);
      o4.z = f2bf(oacc[fn][2] * rinv);
      o4.w = f2bf(oacc[fn][3] * rinv);
      *(ushort4*)&orow[fn * 16 + lg * 4] = o4;
    }
  }
}

extern "C" void kernel_launch(void* const* d_in, const int* in_sizes, int n_in,
                              void* d_out, int out_size, void* d_ws, size_t ws_size,
                              hipStream_t stream) {
  const float* x  = (const float*)d_in[0];
  const float* Wq = (const float*)d_in[1];
  const float* Wk = (const float*)d_in[2];
  const float* Wv = (const float*)d_in[3];
  const float* Wo = (const float*)d_in[4];
  const float* Wf = (const float*)d_in[5];
  float* out = (float*)d_out;
  char* ws = (char*)d_ws;
  const size_t MB = 1024 * 1024;
  u16* x_bf  = (u16*)(ws + 0);        // 8 MB
  u16* WqkvT = (u16*)(ws + 8 * MB);   // 6 MB: WqT | WkT | WvT contiguous [3072][1024]
  u16* WoT   = (u16*)(ws + 14 * MB);  // 2 MB
  u16* Qw    = (u16*)(ws + 16 * MB);  // 8 MB [bh][n][hd]
  u16* Kw    = (u16*)(ws + 24 * MB);  // 8 MB
  u16* Vw    = (u16*)(ws + 32 * MB);  // 8 MB [bh][hd][n]
  u16* Ow    = (u16*)(ws + 40 * MB);  // 8 MB [b n d]
  float* lf  = (float*)(ws + 48 * MB);            // 256 KB
  float* cwp = (float*)(ws + 48 * MB + 262144);   // 256 KB
  u16* Vtmp  = (u16*)(ws + 49 * MB);  // 8 MB [bh][n][hd]

  transpose_w_kernel<<<dim3(256, 4), 256, 0, stream>>>(Wq, Wk, Wv, Wo, WqkvT);
  logf_kernel<<<4096, 256, 0, stream>>>(x, Wf, lf, x_bf);
  cumsum_kernel<<<32, 64, 0, stream>>>(lf, cwp);
  // fused QKV GEMM: N = 3072
  gemm_kernel<<<dim3(24, 32), 256, 0, stream>>>(x_bf, WqkvT, Qw, Kw, Vtmp, nullptr, 0);
  transpose_v_kernel<<<dim3(32, 32), 256, 0, stream>>>(Vtmp, Vw);
  attn_kernel<<<dim3(16, 32), 256, 0, stream>>>(Qw, Kw, Vw, cwp, Ow);
  gemm_kernel<<<dim3(8, 32), 256, 0, stream>>>(Ow, WqkvT + (size_t)3 * DD * DD, nullptr, nullptr, nullptr, out, 1);
}

// Round 8
// 129.771 us; speedup vs baseline: 1.1375x; 1.0403x over previous
//
#include <hip/hip_runtime.h>
#include <hip/hip_bf16.h>
#include <stdint.h>

#define NN 2048
#define DD 1024
#define HH 16
#define HDD 64
#define QBLK 64
#define KVBLK 64

typedef unsigned short u16;
typedef __attribute__((ext_vector_type(8))) __bf16 bf16x8_t;
typedef __attribute__((ext_vector_type(4))) float f32x4_t;

static __device__ __forceinline__ u16 f2bf(float f) {
  union { float f; uint32_t u; } v; v.f = f;
  uint32_t r = v.u + 0x7FFFu + ((v.u >> 16) & 1u);
  return (u16)(r >> 16);
}

static __device__ __forceinline__ uint32_t packbf2(float a, float b) {
  __hip_bfloat162 h2 = __float22bfloat162_rn(make_float2(a, b));
  union { __hip_bfloat162 hh; uint32_t u; } cvt; cvt.hh = h2;
  return cvt.u;
}

// async global->LDS, 16B per lane. LDS dest must be wave-uniform base + lane*16.
static __device__ __forceinline__ void async_copy16(const void* g, void* l) {
  __builtin_amdgcn_global_load_lds((const __attribute__((address_space(1))) void*)g,
                                   (__attribute__((address_space(3))) void*)l, 16, 0, 0);
}

// ---------------- weight transpose+cast: Wt[n][k] = W[k][n], 4 weights in one launch ----------------
__global__ void transpose_w_kernel(const float* __restrict__ W0, const float* __restrict__ W1,
                                   const float* __restrict__ W2, const float* __restrict__ W3,
                                   u16* __restrict__ Wt) {
  __shared__ float tile[64][65];
  const float* W = blockIdx.y == 0 ? W0 : blockIdx.y == 1 ? W1 : blockIdx.y == 2 ? W2 : W3;
  u16* out = Wt + (size_t)blockIdx.y * DD * DD;
  int bx = blockIdx.x & 15;   // n tile
  int by = blockIdx.x >> 4;   // k tile
  int t = threadIdx.x;
  int c = t & 63, r4 = t >> 6;
#pragma unroll
  for (int i = 0; i < 16; i++) {
    int row = i * 4 + r4;
    tile[row][c] = W[(by * 64 + row) * DD + bx * 64 + c];
  }
  __syncthreads();
#pragma unroll
  for (int i = 0; i < 16; i++) {
    int row = i * 4 + r4;
    out[(bx * 64 + row) * DD + by * 64 + c] = f2bf(tile[c][row]);
  }
}

// ---------------- log-sigmoid gate + fused x->bf16 cast ----------------
__global__ void logf_kernel(const float* __restrict__ x, const float* __restrict__ Wf,
                            float* __restrict__ lf, u16* __restrict__ xb) {
  __shared__ float xs[DD];
  __shared__ float part[16][17];
  int row = blockIdx.x;   // b*N + n
  int t = threadIdx.x;    // 256
  float4 v = *(const float4*)&x[(size_t)row * DD + t * 4];
  *(float4*)&xs[t * 4] = v;
  ushort4 o;
  o.x = f2bf(v.x); o.y = f2bf(v.y); o.z = f2bf(v.z); o.w = f2bf(v.w);
  *(ushort4*)&xb[(size_t)row * DD + t * 4] = o;
  __syncthreads();
  int h = t & 15, chunk = t >> 4;
  float s = 0.f;
#pragma unroll 8
  for (int e = 0; e < 64; e++)
    s += xs[chunk * 64 + e] * Wf[(chunk * 64 + e) * HH + h];
  part[chunk][h] = s;
  __syncthreads();
  if (t < 16) {
    float z = 0.f;
#pragma unroll
    for (int i = 0; i < 16; i++) z += part[i][t];
    float ls = fminf(z, 0.f) - log1pf(__expf(-fabsf(z)));
    int b = row >> 11, n = row & (NN - 1);
    lf[(b * HH + t) * NN + n] = ls;
  }
}

// ---------------- cumsum over n per (b,h): float4/lane, 8 outer iters ----------------
__global__ void cumsum_kernel(const float* __restrict__ lf, float* __restrict__ c) {
  int bh = blockIdx.x;
  int lane = threadIdx.x;  // 64
  const float* in = lf + bh * NN;
  float* out = c + bh * NN;
  float carry = 0.f;
  for (int t0 = 0; t0 < NN; t0 += 256) {
    float4 v = *(const float4*)&in[t0 + lane * 4];
    float s1 = v.x + v.y, s2 = s1 + v.z, s3 = s2 + v.w;
    float incl = s3;
#pragma unroll
    for (int off = 1; off < 64; off <<= 1) {
      float u = __shfl_up(incl, off, 64);
      if (lane >= off) incl += u;
    }
    float excl = incl - s3 + carry;
    float4 o;
    o.x = excl + v.x; o.y = excl + s1; o.z = excl + s2; o.w = excl + s3;
    *(float4*)&out[t0 + lane * 4] = o;
    carry = __shfl(incl, 63, 64) + carry;
  }
}

// ---------------- GEMM 128x128 tile, BK=64, swizzled LDS, 512 threads (8 waves, 2x4) ----------------
// mode 0 (QKV fused): Wt is [3072][1024]; n-range selects oQ/oK/oV, bf16 [bh][n][hd]
// mode 1 (output):    Wt is [1024][1024]; fp32 flat to oF
__global__ __launch_bounds__(512, 4) void gemm_kernel(const u16* __restrict__ A,
                                                      const u16* __restrict__ Wt,
                                                      u16* __restrict__ oQ, u16* __restrict__ oK,
                                                      u16* __restrict__ oV, float* __restrict__ oF,
                                                      int mode) {
  __shared__ u16 Als[128 * 64];
  __shared__ u16 Bls[128 * 64];
  int m0 = blockIdx.y * 128, n0 = blockIdx.x * 128;
  int tid = threadIdx.x;
  int lane = tid & 63, w = tid >> 6;   // 8 waves
  int wm = w >> 2, wn = w & 3;         // 2 x 4 wave grid: 64 rows x 32 cols each
  int lr = lane & 15, lg = lane >> 4;

  // staging: slots s = tid + j*512 (j=0..1). row = s>>3, chunk = s&7 (16B units).
  // LDS linear at s*16; swizzle folded into SOURCE chunk: chunk ^ (row&7).
  const u16* gA[2]; const u16* gB[2]; u16* lA[2]; u16* lB[2];
#pragma unroll
  for (int j = 0; j < 2; j++) {
    int s = tid + j * 512;
    int row = s >> 3, ch = s & 7;
    int scol = (ch ^ (row & 7)) * 8;
    gA[j] = &A [(size_t)(m0 + row) * DD + scol];
    gB[j] = &Wt[(size_t)(n0 + row) * DD + scol];
    lA[j] = &Als[s * 8];
    lB[j] = &Bls[s * 8];
  }

  f32x4_t acc[4][2];
#pragma unroll
  for (int i = 0; i < 4; i++)
#pragma unroll
    for (int j = 0; j < 2; j++) acc[i][j] = (f32x4_t){0.f, 0.f, 0.f, 0.f};

  for (int kt = 0; kt < DD; kt += 64) {
    __syncthreads();
#pragma unroll
    for (int j = 0; j < 2; j++) {
      async_copy16(gA[j] + kt, lA[j]);
      async_copy16(gB[j] + kt, lB[j]);
    }
    __syncthreads();
#pragma unroll
    for (int kk = 0; kk < 2; kk++) {
      bf16x8_t af[4], bfv[2];
#pragma unroll
      for (int mi = 0; mi < 4; mi++) {
        int row = wm * 64 + mi * 16 + lr;
        int boff = (row * 128 + kk * 64 + lg * 16) ^ ((row & 7) << 4);
        af[mi] = *(const bf16x8_t*)((const char*)Als + boff);
      }
#pragma unroll
      for (int ni = 0; ni < 2; ni++) {
        int row = wn * 32 + ni * 16 + lr;
        int boff = (row * 128 + kk * 64 + lg * 16) ^ ((row & 7) << 4);
        bfv[ni] = *(const bf16x8_t*)((const char*)Bls + boff);
      }
#pragma unroll
      for (int mi = 0; mi < 4; mi++)
#pragma unroll
        for (int ni = 0; ni < 2; ni++)
          acc[mi][ni] = __builtin_amdgcn_mfma_f32_16x16x32_bf16(af[mi], bfv[ni], acc[mi][ni], 0, 0, 0);
    }
  }

  if (mode == 1) {
#pragma unroll
    for (int mi = 0; mi < 4; mi++)
#pragma unroll
      for (int ni = 0; ni < 2; ni++) {
        int gcol = n0 + wn * 32 + ni * 16 + lr;
#pragma unroll
        for (int r = 0; r < 4; r++) {
          int grow = m0 + wm * 64 + mi * 16 + lg * 4 + r;
          oF[(size_t)grow * DD + gcol] = acc[mi][ni][r];
        }
      }
  } else {
    int which = n0 >> 10;
    u16* outp = which == 0 ? oQ : which == 1 ? oK : oV;
    int nl0 = n0 & 1023;
#pragma unroll
    for (int mi = 0; mi < 4; mi++)
#pragma unroll
      for (int ni = 0; ni < 2; ni++) {
        int gcol = nl0 + wn * 32 + ni * 16 + lr;
        int h = gcol >> 6, hd = gcol & 63;
#pragma unroll
        for (int r = 0; r < 4; r++) {
          int grow = m0 + wm * 64 + mi * 16 + lg * 4 + r;
          int b = grow >> 11, n = grow & (NN - 1);
          outp[((size_t)(b * HH + h) * NN + n) * HDD + hd] = f2bf(acc[mi][ni][r]);
        }
      }
  }
}

// ---------------- V transpose: [bh][n][hd] -> [bh][hd][n] ----------------
__global__ void transpose_v_kernel(const u16* __restrict__ Vtmp, u16* __restrict__ Vt) {
  __shared__ u16 tile[64][80];
  int bh = blockIdx.y;
  int n0 = blockIdx.x * 64;
  int t = threadIdx.x;
  const u16* src = Vtmp + (size_t)bh * NN * HDD;
  u16* dst = Vt + (size_t)bh * HDD * NN;
#pragma unroll
  for (int it = 0; it < 2; it++) {
    int cc = t + it * 256;
    int row = cc >> 3, p = cc & 7;
    *(uint4*)&tile[row][p * 8] = *(const uint4*)&src[(size_t)(n0 + row) * HDD + p * 8];
  }
  __syncthreads();
#pragma unroll
  for (int it = 0; it < 2; it++) {
    int cc = t + it * 256;
    int row = cc >> 3, p = cc & 7;
    union { u16 v[8]; uint4 q; } tmp;
#pragma unroll
    for (int e = 0; e < 8; e++) tmp.v[e] = tile[p * 8 + e][row];
    *(uint4*)&dst[(size_t)row * NN + n0 + p * 8] = tmp.q;
  }
}

// ---------------- flash attention, SWAPPED QK^T, P in registers via permlane swaps ----------------
// Lane (lr,lg) after S^T=mfma(K,Q) holds P quarters q = 4f+lg of its own q-row (i=lr).
// B-fragment for PV needs k-slots 32s+8lg+e: built with 2x permlane32_swap + 2x
// permlane16_swap per half -- no P LDS round-trip at all.
__global__ __launch_bounds__(256) void attn_kernel(const u16* __restrict__ Q,
                                                   const u16* __restrict__ K,
                                                   const u16* __restrict__ Vt,
                                                   const float* __restrict__ cw,
                                                   u16* __restrict__ O) {
  __shared__ u16 Kls[2][KVBLK * 64];
  __shared__ u16 Vls[2][64 * KVBLK];
  int flat = blockIdx.y * gridDim.x + blockIdx.x;  // grid (16, 32) = 512
  int swz = (flat & 7) * 64 + (flat >> 3);         // bijective, bh-contiguous per XCD
  int pidx = swz & 15, bh = swz >> 4;
  int tid = threadIdx.x;
  int lane = tid & 63, w = tid >> 6;
  int lr = lane & 15, lg = lane >> 4;
  const u16* Qh = Q + (size_t)bh * NN * HDD;
  const u16* Kh = K + (size_t)bh * NN * HDD;
  const u16* Vh = Vt + (size_t)bh * HDD * NN;
  const float* ch = cw + bh * NN;
  int b = bh >> 4, h = bh & 15;

  // staging: 512 slots of 16B per 8KB tile; LDS linear at slot*16B;
  // swizzle folded into SOURCE chunk: chunk ^ (row&7).
  int s0 = tid, s1 = tid + 256;
  int r0 = s0 >> 3, p0 = s0 & 7;
  int r1 = s1 >> 3, p1 = s1 & 7;
  const u16* gk0 = &Kh[(size_t)r0 * HDD + ((p0 ^ (r0 & 7)) * 8)];
  const u16* gk1 = &Kh[(size_t)r1 * HDD + ((p1 ^ (r1 & 7)) * 8)];
  const u16* gv0 = &Vh[(size_t)r0 * NN + ((p0 ^ (r0 & 7)) * 8)];
  const u16* gv1 = &Vh[(size_t)r1 * NN + ((p1 ^ (r1 & 7)) * 8)];

  for (int which = 0; which < 2; which++) {
    int tile = which == 0 ? (31 - pidx) : pidx;
    int qb = tile * QBLK + w * 16;
    int iq = qb + lr;  // this lane's q-row

    bf16x8_t qf[2];
#pragma unroll
    for (int s = 0; s < 2; s++)
      qf[s] = *(const bf16x8_t*)&Qh[(size_t)iq * HDD + s * 32 + lg * 8];
    float cq = ch[iq];

    float lsum = 0.f;
    f32x4_t oacc[4];
#pragma unroll
    for (int fn = 0; fn < 4; fn++) oacc[fn] = (f32x4_t){0.f, 0.f, 0.f, 0.f};

    // prologue: stage kv tile 0 into buffer 0
    async_copy16(gk0, &Kls[0][s0 * 8]);
    async_copy16(gk1, &Kls[0][s1 * 8]);
    async_copy16(gv0, &Vls[0][s0 * 8]);
    async_copy16(gv1, &Vls[0][s1 * 8]);
    __syncthreads();

    int cur = 0;
    for (int kvt = 0; kvt <= tile; kvt++) {
      // stage next tile into the other buffer BEFORE computing this one
      if (kvt < tile) {
        int nb = cur ^ 1;
        size_t kvn = (size_t)(kvt + 1) * KVBLK;
        async_copy16(gk0 + kvn * HDD, &Kls[nb][s0 * 8]);
        async_copy16(gk1 + kvn * HDD, &Kls[nb][s1 * 8]);
        async_copy16(gv0 + kvn, &Vls[nb][s0 * 8]);
        async_copy16(gv1 + kvn, &Vls[nb][s1 * 8]);
      }
      int kv0 = kvt * KVBLK;
      const u16* Kb = Kls[cur];
      const u16* Vb = Vls[cur];
      float4 ckv[4];
#pragma unroll
      for (int f = 0; f < 4; f++)
        ckv[f] = *(const float4*)&ch[kv0 + f * 16 + lg * 4];

      // S^T = K . Q^T : lane holds col i=lr, rows j = kv0 + f*16 + lg*4 + r
      f32x4_t sacc[4];
#pragma unroll
      for (int f = 0; f < 4; f++) sacc[f] = (f32x4_t){0.f, 0.f, 0.f, 0.f};
      __builtin_amdgcn_s_setprio(1);
#pragma unroll
      for (int f = 0; f < 4; f++) {
        int row = f * 16 + lr;
#pragma unroll
        for (int s = 0; s < 2; s++) {
          int boff = (row * 128 + s * 64 + lg * 16) ^ ((row & 7) << 4);
          bf16x8_t kf = *(const bf16x8_t*)((const char*)Kb + boff);
          sacc[f] = __builtin_amdgcn_mfma_f32_16x16x32_bf16(kf, qf[s], sacc[f], 0, 0, 0);
        }
      }
      __builtin_amdgcn_s_setprio(0);

      // fixed-max softmax: e = exp(s*scale + cq - ck); scalar lsum
      bool diag = (kvt == tile);
      float pv[4][4];
#pragma unroll
      for (int f = 0; f < 4; f++) {
        const float* ckp = &ckv[f].x;
#pragma unroll
        for (int r = 0; r < 4; r++) {
          float val = fmaf(sacc[f][r], 0.125f, cq - ckp[r]);
          float e = __expf(val);
          if (diag && (kv0 + f * 16 + lg * 4 + r) > iq) e = 0.f;
          pv[f][r] = e; lsum += e;
        }
      }

      // pack P quarters to bf16 pairs: wq[f][0] = (r0,r1), wq[f][1] = (r2,r3)
      uint32_t wq[4][2];
#pragma unroll
      for (int f = 0; f < 4; f++) {
        wq[f][0] = packbf2(pv[f][0], pv[f][1]);
        wq[f][1] = packbf2(pv[f][2], pv[f][3]);
      }
      // permlane network: pa[s] words = {c0,c1,c2,c3}; s-half uses f = 2s, 2s+1
      bf16x8_t pa[2];
#pragma unroll
      for (int s = 0; s < 2; s++) {
        uint32_t x0 = wq[2 * s][0], x1 = wq[2 * s][1];
        uint32_t y0 = wq[2 * s + 1][0], y1 = wq[2 * s + 1][1];
        asm volatile("v_permlane32_swap_b32 %0, %1" : "+v"(x0), "+v"(y0));
        asm volatile("v_permlane32_swap_b32 %0, %1" : "+v"(x1), "+v"(y1));
        asm volatile("v_permlane16_swap_b32 %0, %1" : "+v"(x0), "+v"(y0));
        asm volatile("v_permlane16_swap_b32 %0, %1" : "+v"(x1), "+v"(y1));
        union { uint32_t u[4]; bf16x8_t v; } pk;
        pk.u[0] = x0; pk.u[1] = x1; pk.u[2] = y0; pk.u[3] = y1;
        pa[s] = pk.v;
      }

      // O^T += V^T . P : A = V^T rows (m=d), B = P (n=i)
      __builtin_amdgcn_s_setprio(1);
#pragma unroll
      for (int fn = 0; fn < 4; fn++) {
        int row = fn * 16 + lr;
#pragma unroll
        for (int s = 0; s < 2; s++) {
          int boff = (row * 128 + s * 64 + lg * 16) ^ ((row & 7) << 4);
          bf16x8_t vf = *(const bf16x8_t*)((const char*)Vb + boff);
          oacc[fn] = __builtin_amdgcn_mfma_f32_16x16x32_bf16(vf, pa[s], oacc[fn], 0, 0, 0);
        }
      }
      __builtin_amdgcn_s_setprio(0);
      __syncthreads();
      cur ^= 1;
    }

    // l-reduce over the 4 lanes sharing lr
    lsum += __shfl_xor(lsum, 16, 64);
    lsum += __shfl_xor(lsum, 32, 64);
    float rinv = 1.0f / lsum;

    // output: lane's q-row iq, hd = fn*16 + lg*4 + r -> packed 8B stores
    u16* orow = O + ((size_t)(b * NN + iq)) * DD + h * HDD;
#pragma unroll
    for (int fn = 0; fn < 4; fn++) {
      ushort4 o4;
      o4.x = f2bf(oacc[fn][0] * rinv);
      o4.y = f2bf(oacc[fn][1] * rinv);
      o4.z = f2bf(oacc[fn][2] * rinv);
      o4.w = f2bf(oacc[fn][3] * rinv);
      *(ushort4*)&orow[fn * 16 + lg * 4] = o4;
    }
  }
}

extern "C" void kernel_launch(void* const* d_in, const int* in_sizes, int n_in,
                              void* d_out, int out_size, void* d_ws, size_t ws_size,
                              hipStream_t stream) {
  const float* x  = (const float*)d_in[0];
  const float* Wq = (const float*)d_in[1];
  const float* Wk = (const float*)d_in[2];
  const float* Wv = (const float*)d_in[3];
  const float* Wo = (const float*)d_in[4];
  const float* Wf = (const float*)d_in[5];
  float* out = (float*)d_out;
  char* ws = (char*)d_ws;
  const size_t MB = 1024 * 1024;
  u16* x_bf  = (u16*)(ws + 0);        // 8 MB
  u16* WqkvT = (u16*)(ws + 8 * MB);   // 6 MB: WqT | WkT | WvT contiguous [3072][1024]
  u16* WoT   = (u16*)(ws + 14 * MB);  // 2 MB
  u16* Qw    = (u16*)(ws + 16 * MB);  // 8 MB [bh][n][hd]
  u16* Kw    = (u16*)(ws + 24 * MB);  // 8 MB
  u16* Vw    = (u16*)(ws + 32 * MB);  // 8 MB [bh][hd][n]
  u16* Ow    = (u16*)(ws + 40 * MB);  // 8 MB [b n d]
  float* lf  = (float*)(ws + 48 * MB);            // 256 KB
  float* cwp = (float*)(ws + 48 * MB + 262144);   // 256 KB
  u16* Vtmp  = (u16*)(ws + 49 * MB);  // 8 MB [bh][n][hd]

  transpose_w_kernel<<<dim3(256, 4), 256, 0, stream>>>(Wq, Wk, Wv, Wo, WqkvT);
  logf_kernel<<<4096, 256, 0, stream>>>(x, Wf, lf, x_bf);
  cumsum_kernel<<<32, 64, 0, stream>>>(lf, cwp);
  // fused QKV GEMM: N = 3072
  gemm_kernel<<<dim3(24, 32), 512, 0, stream>>>(x_bf, WqkvT, Qw, Kw, Vtmp, nullptr, 0);
  transpose_v_kernel<<<dim3(32, 32), 256, 0, stream>>>(Vtmp, Vw);
  attn_kernel<<<dim3(16, 32), 256, 0, stream>>>(Qw, Kw, Vw, cwp, Ow);
  gemm_kernel<<<dim3(8, 32), 512, 0, stream>>>(Ow, WqkvT + (size_t)3 * DD * DD, nullptr, nullptr, nullptr, out, 1);
}